// Round 3
// baseline (238.918 us; speedup 1.0000x reference)
//
#include <hip/hip_runtime.h>
#include <hip/hip_bf16.h>

typedef unsigned short u16;
typedef __attribute__((ext_vector_type(8))) short short8;
typedef __attribute__((ext_vector_type(4))) float floatx4;

__device__ __forceinline__ u16 f32_to_bf16_rne(float f) {
  union { float f; unsigned int u; } v; v.f = f;
  unsigned int u = v.u;
  u += 0x7FFFu + ((u >> 16) & 1u);
  return (u16)(u >> 16);
}

__device__ __forceinline__ short8 pack_bf16x8(const float* v) {
  short8 pk;
  #pragma unroll
  for (int j = 0; j < 4; ++j) {
    __hip_bfloat162 h2 = __float22bfloat162_rn(make_float2(v[2 * j], v[2 * j + 1]));
    union { __hip_bfloat162 h; struct { short lo, hi; } s; } u; u.h = h2;
    pk[2 * j] = u.s.lo; pk[2 * j + 1] = u.s.hi;
  }
  return pk;
}

// ---------------- Kernel 1: global average pool ----------------
// grid 8192 = B*C blocks, 256 threads. pooled[b*256+c] = mean over 3136.
// Side effect: streams all of x -> x becomes L3-resident for the GEMM.
__global__ __launch_bounds__(256) void pool_kernel(const float* __restrict__ x,
                                                   float* __restrict__ pooled) {
  const int bc = blockIdx.x;
  const float4* row = (const float4*)(x + (size_t)bc * 3136);
  const int t = threadIdx.x;
  float s = 0.0f;
  for (int q = t; q < 784; q += 256) {   // 784 float4 = 3136 floats
    float4 v = row[q];
    s += (v.x + v.y) + (v.z + v.w);
  }
  #pragma unroll
  for (int off = 32; off > 0; off >>= 1) s += __shfl_down(s, off, 64);
  __shared__ float red[4];
  if ((t & 63) == 0) red[t >> 6] = s;
  __syncthreads();
  if (t == 0) pooled[bc] = (red[0] + red[1] + red[2] + red[3]) * (1.0f / 3136.0f);
}

// ---------------- Kernel 2: attention MLP + w_dyn (bf16), 4-b batched --------
// grid 256 = 32 o-chunks (8 rows each) x 8 b-quads. Each weights element is
// read by 8 blocks (was 32) -> L2 weights traffic 256 MB -> 67 MB.
__global__ __launch_bounds__(256) void attn_wdyn_kernel3(
    const float* __restrict__ pooled, const float* __restrict__ weights,
    const float* __restrict__ w1, const float* __restrict__ b1,
    const float* __restrict__ w2, const float* __restrict__ b2,
    u16* __restrict__ wdyn) {
  const int blk = blockIdx.x;
  const int bq  = blk & 7;     // batch quad: b = bq*4 + bb
  const int ocg = blk >> 3;    // o-chunk: rows ocg*8 .. ocg*8+7
  const int t = threadIdx.x;
  __shared__ float ph[256];
  __shared__ float part[256];
  __shared__ float hb[64];
  __shared__ float lg[8];

  float a[4][8];   // softmax weights for 4 batches

  for (int bb = 0; bb < 4; ++bb) {
    const int b = bq * 4 + bb;
    ph[t] = pooled[b * 256 + t];
    __syncthreads();
    {
      const int row = t >> 2, seg = t & 3;
      const float* wr = w1 + row * 256 + seg * 64;
      const float* pp = ph + seg * 64;
      float s = 0.0f;
      #pragma unroll 8
      for (int c = 0; c < 64; ++c) s += pp[c] * wr[c];
      part[t] = s;
    }
    __syncthreads();
    if (t < 64) {
      float s = part[t * 4] + part[t * 4 + 1] + part[t * 4 + 2] + part[t * 4 + 3] + b1[t];
      hb[t] = fmaxf(s, 0.0f);
    }
    __syncthreads();
    if (t < 64) {
      const int row = t >> 3, seg = t & 7;
      const float* wr = w2 + row * 64 + seg * 8;
      float s = 0.0f;
      #pragma unroll
      for (int j = 0; j < 8; ++j) s += hb[seg * 8 + j] * wr[j];
      part[t] = s;
    }
    __syncthreads();
    if (t < 8) {
      float s = b2[t];
      #pragma unroll
      for (int j = 0; j < 8; ++j) s += part[t * 8 + j];
      lg[t] = s;
    }
    __syncthreads();
    {
      float mx = lg[0];
      #pragma unroll
      for (int e = 1; e < 8; ++e) mx = fmaxf(mx, lg[e]);
      float sum = 0.0f;
      #pragma unroll
      for (int e = 0; e < 8; ++e) { a[bb][e] = __expf(lg[e] - mx); sum += a[bb][e]; }
      float inv = 1.0f / sum;
      #pragma unroll
      for (int e = 0; e < 8; ++e) a[bb][e] *= inv;
    }
    __syncthreads();   // protect lg/ph before next bb overwrites
  }

  // wdyn: load weights row once, reuse across 4 batches
  #pragma unroll
  for (int oi = 0; oi < 8; ++oi) {
    const int o = ocg * 8 + oi;
    float w8[8];
    #pragma unroll
    for (int e = 0; e < 8; ++e)
      w8[e] = weights[((size_t)e * 256 + o) * 256 + t];
    #pragma unroll
    for (int bb = 0; bb < 4; ++bb) {
      float acc = 0.0f;
      #pragma unroll
      for (int e = 0; e < 8; ++e) acc += a[bb][e] * w8[e];
      wdyn[((size_t)(bq * 4 + bb) * 256 + o) * 256 + t] = f32_to_bf16_rne(acc);
    }
  }
}

// ---------------- Kernel 3: batched GEMM out[b] = Wdyn[b] @ X[b] -------------
// M=256, N=3136, K=256. Tile BM=256 x BN=128 x BK=32, 4 waves.
// Each wave owns 128m x 64n -> 32 MFMA per K-step (2x the old ratio vs
// staging+barrier). A (Wdyn) direct global->VGPR from L2, prefetched 1 tile.
// X double-buffered in LDS, XOR chunk involution on write & read (2-way, free).
// Grid: 1D 800 = 8 XCD x 100, swizzled so each XCD sees only 4 batches' wdyn
// (524 KB < 4 MB per-XCD L2). Last n-block (nb=24) masked.
#define BK 32

__global__ __launch_bounds__(256, 2) void dynconv_gemm4(
    const float* __restrict__ x, const u16* __restrict__ wdyn,
    float* __restrict__ out) {
  // bijective XCD swizzle: 800 % 8 == 0
  const int bid = blockIdx.x;
  const int nid = (bid & 7) * 100 + (bid >> 3);
  const int b  = nid / 25;
  const int nb = nid % 25;
  const int t = threadIdx.x;
  const int lane = t & 63;
  const int wv = t >> 6;
  const int mh = wv >> 1;          // m-half (128 rows)
  const int nh = wv & 1;           // n-half (64 cols)
  const int quad = lane >> 4;
  const int l16 = lane & 15;
  const int n0 = nb * 128;

  __shared__ __align__(16) u16 Xs[2][128 * BK];   // 2 x 8 KB

  const u16* wb = wdyn + (size_t)b * 65536;
  const float* xb = x + (size_t)b * (256 * 3136);
  float* ob = out + (size_t)b * (256 * 3136);

  // ---- X staging assignment: thread t -> n=t&127, k-half=t>>7 (16 rows) ----
  const int sn  = t & 127;
  const int skg = t >> 7;
  const int ss  = (sn >> 1) & 3;                      // swizzle key (row-derived)
  const int sbase = sn * BK + ((skg ^ (ss >> 1)) * 16); // u16 offset of 32B slot
  const bool sswap = (ss & 1) != 0;
  const float* xcp = xb + min(n0 + sn, 3135);         // clamp (mask at store)

  // ---- fragment read assignment ----
  const int rch = (quad ^ ((l16 >> 1) & 3)) * 8;      // same involution as write
  const u16* wfp = wb + (size_t)(mh * 128 + l16) * 256 + quad * 8;

  floatx4 acc[8][4];
  #pragma unroll
  for (int i = 0; i < 8; ++i)
    #pragma unroll
    for (int j = 0; j < 4; ++j) acc[i][j] = (floatx4)(0.0f);

  // ---- prologue: stage tile 0, load A tile 0 ----
  short8 wcur[8];
  #pragma unroll
  for (int mt = 0; mt < 8; ++mt)
    wcur[mt] = *(const short8*)(wfp + (size_t)mt * 16 * 256);
  {
    float xr[16];
    #pragma unroll
    for (int j = 0; j < 16; ++j) xr[j] = xcp[(size_t)(skg * 16 + j) * 3136];
    short8 plo = pack_bf16x8(xr), phi = pack_bf16x8(xr + 8);
    *(short8*)(&Xs[0][sbase])     = sswap ? phi : plo;
    *(short8*)(&Xs[0][sbase + 8]) = sswap ? plo : phi;
  }
  __syncthreads();

  int cur = 0;
  for (int kt = 0; kt < 8; ++kt) {
    // issue next tile's loads before compute (latency hides under MFMA)
    short8 wnxt[8];
    float xr[16];
    if (kt < 7) {
      const int k1 = (kt + 1) * BK;
      #pragma unroll
      for (int j = 0; j < 16; ++j) xr[j] = xcp[(size_t)(k1 + skg * 16 + j) * 3136];
      #pragma unroll
      for (int mt = 0; mt < 8; ++mt)
        wnxt[mt] = *(const short8*)(wfp + (size_t)mt * 16 * 256 + k1);
    }
    // MFMA on current tile
    short8 bfr[4];
    #pragma unroll
    for (int nt = 0; nt < 4; ++nt)
      bfr[nt] = *(const short8*)(&Xs[cur][(nh * 64 + nt * 16 + l16) * BK + rch]);
    #pragma unroll
    for (int mt = 0; mt < 8; ++mt)
      #pragma unroll
      for (int nt = 0; nt < 4; ++nt)
        acc[mt][nt] = __builtin_amdgcn_mfma_f32_16x16x32_bf16(
            wcur[mt], bfr[nt], acc[mt][nt], 0, 0, 0);
    // stage next X tile, rotate A prefetch
    if (kt < 7) {
      short8 plo = pack_bf16x8(xr), phi = pack_bf16x8(xr + 8);
      *(short8*)(&Xs[cur ^ 1][sbase])     = sswap ? phi : plo;
      *(short8*)(&Xs[cur ^ 1][sbase + 8]) = sswap ? plo : phi;
      #pragma unroll
      for (int mt = 0; mt < 8; ++mt) wcur[mt] = wnxt[mt];
    }
    __syncthreads();
    cur ^= 1;
  }

  // ---- epilogue: C/D col=l16 (n), row=quad*4+reg (m); mask OOB n ----
  #pragma unroll
  for (int mt = 0; mt < 8; ++mt) {
    const int orow = mh * 128 + mt * 16 + quad * 4;
    #pragma unroll
    for (int nt = 0; nt < 4; ++nt) {
      const int n = n0 + nh * 64 + nt * 16 + l16;
      if (n < 3136) {
        #pragma unroll
        for (int rg = 0; rg < 4; ++rg)
          ob[(size_t)(orow + rg) * 3136 + n] = acc[mt][nt][rg];
      }
    }
  }
}

extern "C" void kernel_launch(void* const* d_in, const int* in_sizes, int n_in,
                              void* d_out, int out_size, void* d_ws, size_t ws_size,
                              hipStream_t stream) {
  const float* x       = (const float*)d_in[0];
  const float* weights = (const float*)d_in[1];
  const float* w1      = (const float*)d_in[2];
  const float* b1      = (const float*)d_in[3];
  const float* w2      = (const float*)d_in[4];
  const float* b2      = (const float*)d_in[5];
  float* out = (float*)d_out;

  float* pooled = (float*)d_ws;                       // 32 KB
  u16* wdyn = (u16*)((char*)d_ws + 32768);            // 4 MB bf16 [32][256][256]

  pool_kernel<<<8192, 256, 0, stream>>>(x, pooled);
  attn_wdyn_kernel3<<<256, 256, 0, stream>>>(pooled, weights, w1, b1, w2, b2, wdyn);
  dynconv_gemm4<<<800, 256, 0, stream>>>(x, wdyn, out);
}